// Round 6
// baseline (83.786 us; speedup 1.0000x reference)
//
#include <hip/hip_runtime.h>
#include <hip/hip_bf16.h>

// N=4096, PAIR=2, M=64, D=128, O=128, R=2, MAX_DEG=32
// h = relu(x @ (d*Wsum + W0) + (d*bsum + b0));  out[n] = h0 @ h1^T
//
// Round 6: node-level software pipeline. 1024 blocks x 4 consecutive nodes.
// Separate LDS regions (W 32K | h 32K) -> no W/h aliasing, 2 barriers/node.
// Per node: W(d_next)+x_next issued BEFORE GEMM1 so HBM latency hides under
// compute and every wave issues loads every node period (duty-cycle fix).

typedef __attribute__((ext_vector_type(8))) short bf16x8;
typedef __attribute__((ext_vector_type(4))) float f32x4;

__device__ __forceinline__ unsigned int pkbf(float a, float b) {
    union { __hip_bfloat162 h; unsigned int u; } v;
    v.h = __float22bfloat162_rn(float2{a, b});
    return v.u;
}

__global__ __launch_bounds__(256) void build_weights(
    const float* __restrict__ W_r,  // [2,128,128]
    const float* __restrict__ b_r,  // [2,128]
    const float* __restrict__ W0,   // [128,128]
    const float* __restrict__ b0,   // [128]
    unsigned short* __restrict__ wfrag,  // [32][8*4*64*8]  (32 KB per deg)
    float* __restrict__ call)            // [32*128]
{
    int t = blockIdx.x * blockDim.x + threadIdx.x;   // 0..65535
    int lane = t & 63;
    int ks = (t >> 6) & 3;
    int ct = (t >> 8) & 7;
    int d  = (t >> 11) & 31;
    int o = ct * 16 + (lane & 15);
    int kbase = ks * 32 + (lane >> 4) * 8;
    unsigned int* dst = (unsigned int*)(wfrag + (size_t)t * 8);
#pragma unroll
    for (int j = 0; j < 4; ++j) {
        int k0 = kbase + 2 * j;
        float wA = (float)d * (W_r[k0 * 128 + o] + W_r[128 * 128 + k0 * 128 + o]) + W0[k0 * 128 + o];
        float wB = (float)d * (W_r[(k0 + 1) * 128 + o] + W_r[128 * 128 + (k0 + 1) * 128 + o]) + W0[(k0 + 1) * 128 + o];
        dst[j] = pkbf(wA, wB);
    }
    if (t < 32 * 128) {
        int dd = t >> 7, oo = t & 127;
        call[t] = (float)dd * (b_r[oo] + b_r[128 + oo]) + b0[oo];
    }
}

__global__ __launch_bounds__(256, 2) void edge_kernel(
    const float* __restrict__ x,    // [N,2,64,128] f32
    const int* __restrict__ deg,    // [N]
    const unsigned short* __restrict__ wfrag,
    const float* __restrict__ call,
    float* __restrict__ out)        // [N,64,64] f32
{
    __shared__ char wlds[32768];   // W_eff[d] fragments for current node
    __shared__ char hlds[32768];   // h tile (o-tile-major, slot-XOR layout)

    const int tid = threadIdx.x;
    const int wave = tid >> 6;
    const int lane = tid & 63;
    const int l15 = lane & 15;
    const int lhi = lane >> 4;      // 0..3
    const int rbase = wave * 32;
    const int b4 = blockIdx.x * 4;

    int dg[4];
#pragma unroll
    for (int j = 0; j < 4; ++j) dg[j] = deg[b4 + j];

    f32x4 xraw[2][4][2];
    auto issue_x = [&](int n) {
        const float* xn = x + (size_t)n * (2 * 64 * 128);
#pragma unroll
        for (int rt = 0; rt < 2; ++rt) {
            const float* rowp = xn + (size_t)(rbase + rt * 16 + l15) * 128;
#pragma unroll
            for (int ks = 0; ks < 4; ++ks) {
                const f32x4* p = (const f32x4*)(rowp + ks * 32 + lhi * 8);
                xraw[rt][ks][0] = p[0];
                xraw[rt][ks][1] = p[1];
            }
        }
    };

    // ---- prologue: stage W(d0), issue x(node0) ----
    {
        const char* wsrc = (const char*)(wfrag + (size_t)dg[0] * (8 * 4 * 64 * 8));
        f32x4 w0[8];
#pragma unroll
        for (int i = 0; i < 8; ++i)
            w0[i] = *(const f32x4*)(wsrc + i * 4096 + tid * 16);
        issue_x(b4);
#pragma unroll
        for (int i = 0; i < 8; ++i)
            *(f32x4*)(wlds + i * 4096 + tid * 16) = w0[i];
    }
    __syncthreads();

    for (int j = 0; j < 4; ++j) {
        const float* cd = call + dg[j] * 128;

        // bias loads first (older than prefetch -> counted vmcnt waits)
        f32x4 ccv[8];
#pragma unroll
        for (int ct = 0; ct < 8; ++ct)
            ccv[ct] = *(const f32x4*)(cd + ct * 16 + lhi * 4);

        // convert current node's x (waits its loads; cc/prefetch stay in flight)
        bf16x8 afrag[2][4];
#pragma unroll
        for (int rt = 0; rt < 2; ++rt)
#pragma unroll
            for (int ks = 0; ks < 4; ++ks) {
                f32x4 a0 = xraw[rt][ks][0];
                f32x4 a1 = xraw[rt][ks][1];
                union { bf16x8 v; unsigned int u[4]; } f;
                f.u[0] = pkbf(a0.x, a0.y);
                f.u[1] = pkbf(a0.z, a0.w);
                f.u[2] = pkbf(a1.x, a1.y);
                f.u[3] = pkbf(a1.z, a1.w);
                afrag[rt][ks] = f.v;
            }

        // prefetch next node: W frags to regs, x to xraw (hide under GEMMs)
        f32x4 wst[8];
        if (j < 3) {
            const char* wsrc = (const char*)(wfrag + (size_t)dg[j + 1] * (8 * 4 * 64 * 8));
#pragma unroll
            for (int i = 0; i < 8; ++i)
                wst[i] = *(const f32x4*)(wsrc + i * 4096 + tid * 16);
            issue_x(b4 + j + 1);
        }

        // ---- GEMM1 (swapped): D[o][m] = mfma(Wfrag, Xfrag), h -> hlds ----
#pragma unroll
        for (int ct = 0; ct < 8; ++ct) {
            bf16x8 bfrag[4];
#pragma unroll
            for (int ks = 0; ks < 4; ++ks)
                bfrag[ks] = *(const bf16x8*)(wlds + ct * 4096 + ks * 1024 + lane * 16);
            f32x4 acc[2] = {{0.f,0.f,0.f,0.f},{0.f,0.f,0.f,0.f}};
#pragma unroll
            for (int ks = 0; ks < 4; ++ks)
#pragma unroll
                for (int rt = 0; rt < 2; ++rt)
                    acc[rt] = __builtin_amdgcn_mfma_f32_16x16x32_bf16(bfrag[ks], afrag[rt][ks], acc[rt], 0, 0, 0);
            const f32x4 cc4 = ccv[ct];
#pragma unroll
            for (int rt = 0; rt < 2; ++rt) {
                const int m = rbase + rt * 16 + l15;
                const int slot = (lhi >> 1) ^ ((m >> 2) & 1);
                float h0v = fmaxf(acc[rt][0] + cc4.x, 0.f);
                float h1v = fmaxf(acc[rt][1] + cc4.y, 0.f);
                float h2v = fmaxf(acc[rt][2] + cc4.z, 0.f);
                float h3v = fmaxf(acc[rt][3] + cc4.w, 0.f);
                union { unsigned int u[2]; unsigned long long ull; } pk;
                pk.u[0] = pkbf(h0v, h1v);
                pk.u[1] = pkbf(h2v, h3v);
                *(unsigned long long*)(hlds + ct * 4096 + m * 32 + slot * 16 + (lhi & 1) * 8) = pk.ull;
            }
        }
        __syncthreads();   // (A) h complete; all W reads done

        // ---- GEMM2 (swapped): D[q][m] = mfma(h1frag, h0frag) ----
        const int mrow = wave * 16 + l15;     // h0 row (= out row)
        bf16x8 hb[4];
#pragma unroll
        for (int ks = 0; ks < 4; ++ks) {
            const int ct = ks * 2 + (lhi >> 1);
            const int s  = (lhi & 1) ^ ((mrow >> 2) & 1);
            hb[ks] = *(const bf16x8*)(hlds + ct * 4096 + mrow * 32 + s * 16);
        }
        float* outn = out + (size_t)(b4 + j) * 4096;
#pragma unroll
        for (int qt = 0; qt < 4; ++qt) {
            const int qrow = 64 + qt * 16 + l15;    // h1 row (= out col base)
            f32x4 acc = {0.f, 0.f, 0.f, 0.f};
#pragma unroll
            for (int ks = 0; ks < 4; ++ks) {
                const int ct = ks * 2 + (lhi >> 1);
                const int s  = (lhi & 1) ^ ((qrow >> 2) & 1);
                bf16x8 ha = *(const bf16x8*)(hlds + ct * 4096 + qrow * 32 + s * 16);
                acc = __builtin_amdgcn_mfma_f32_16x16x32_bf16(ha, hb[ks], acc, 0, 0, 0);
            }
            *(f32x4*)(outn + mrow * 64 + qt * 16 + lhi * 4) = acc;
        }

        // ---- install next node's W (waits only the 8 W loads) ----
        if (j < 3) {
#pragma unroll
            for (int i = 0; i < 8; ++i)
                *(f32x4*)(wlds + i * 4096 + tid * 16) = wst[i];
        }
        __syncthreads();   // (B) h consumed + new W visible
    }
}

extern "C" void kernel_launch(void* const* d_in, const int* in_sizes, int n_in,
                              void* d_out, int out_size, void* d_ws, size_t ws_size,
                              hipStream_t stream) {
    const float* x   = (const float*)d_in[0];   // node_features [4096,2,64,128]
    const int*   deg = (const int*)d_in[1];     // [4096]
    const float* W_r = (const float*)d_in[2];   // [2,128,128]
    const float* b_r = (const float*)d_in[3];   // [2,128]
    const float* W0  = (const float*)d_in[4];   // [128,128]
    const float* b0  = (const float*)d_in[5];   // [128]
    float* out = (float*)d_out;                 // [4096,64,64]

    unsigned short* wfrag = (unsigned short*)d_ws;                    // 1 MB
    float* call = (float*)((unsigned short*)d_ws + 32 * 8 * 4 * 64 * 8); // +16 KB

    build_weights<<<256, 256, 0, stream>>>(W_r, b_r, W0, b0, wfrag, call);
    edge_kernel<<<1024, 256, 0, stream>>>(x, deg, wfrag, call, out);
}

// Round 8
// 75.150 us; speedup vs baseline: 1.1149x; 1.1149x over previous
//
#include <hip/hip_runtime.h>
#include <hip/hip_bf16.h>

// N=4096, PAIR=2, M=64, D=128, O=128, R=2, MAX_DEG=32
// h = relu(x @ (d*Wsum + W0) + (d*bsum + b0));  out[n] = h0 @ h1^T
//
// Round 7 (fixed): R5 structure (1 node/block, 32 KB aliased W/h LDS,
// 2-ct phases), with register-pressure cuts to raise blocks/CU:
//  - W staged via __builtin_amdgcn_global_load_lds (width 16): no wst regs.
//  - x converted through a 4-deep ring (32 raw VGPR, sched_barrier-pinned)
//    instead of a fully-materialized 64-VGPR xraw array.

typedef __attribute__((ext_vector_type(8))) short bf16x8;
typedef __attribute__((ext_vector_type(4))) float f32x4;

__device__ __forceinline__ unsigned int pkbf(float a, float b) {
    union { __hip_bfloat162 h; unsigned int u; } v;
    v.h = __float22bfloat162_rn(float2{a, b});
    return v.u;
}

__global__ __launch_bounds__(256) void build_weights(
    const float* __restrict__ W_r,  // [2,128,128]
    const float* __restrict__ b_r,  // [2,128]
    const float* __restrict__ W0,   // [128,128]
    const float* __restrict__ b0,   // [128]
    unsigned short* __restrict__ wfrag,  // [32][8*4*64*8]  (32 KB per deg)
    float* __restrict__ call)            // [32*128]
{
    int t = blockIdx.x * blockDim.x + threadIdx.x;   // 0..65535
    int lane = t & 63;
    int ks = (t >> 6) & 3;
    int ct = (t >> 8) & 7;
    int d  = (t >> 11) & 31;
    int o = ct * 16 + (lane & 15);
    int kbase = ks * 32 + (lane >> 4) * 8;
    unsigned int* dst = (unsigned int*)(wfrag + (size_t)t * 8);
#pragma unroll
    for (int j = 0; j < 4; ++j) {
        int k0 = kbase + 2 * j;
        float wA = (float)d * (W_r[k0 * 128 + o] + W_r[128 * 128 + k0 * 128 + o]) + W0[k0 * 128 + o];
        float wB = (float)d * (W_r[(k0 + 1) * 128 + o] + W_r[128 * 128 + (k0 + 1) * 128 + o]) + W0[(k0 + 1) * 128 + o];
        dst[j] = pkbf(wA, wB);
    }
    if (t < 32 * 128) {
        int dd = t >> 7, oo = t & 127;
        call[t] = (float)dd * (b_r[oo] + b_r[128 + oo]) + b0[oo];
    }
}

__global__ __launch_bounds__(256) void edge_kernel(
    const float* __restrict__ x,    // [N,2,64,128] f32
    const int* __restrict__ deg,    // [N]
    const unsigned short* __restrict__ wfrag,
    const float* __restrict__ call,
    float* __restrict__ out)        // [N,64,64] f32
{
    __shared__ char ldsb[32768];   // W staging, then h (o-tile-major, slot-XOR)

    const int n = blockIdx.x;
    const int tid = threadIdx.x;
    const int wave = tid >> 6;
    const int lane = tid & 63;
    const int l15 = lane & 15;
    const int lhi = lane >> 4;      // 0..3
    const int d = deg[n];

    const float* xn = x + (size_t)n * (2 * 64 * 128);
    const char* wsrc = (const char*)(wfrag + (size_t)d * (8 * 4 * 64 * 8));
    const float* cd = call + d * 128;

    // ---- W staging: global -> LDS direct, no VGPR roundtrip ----
    // instr i: lane writes ldsb + i*4096 + wave*1024 + lane*16, from
    // wsrc + i*4096 + tid*16  (identical layout to R5's reg-staged copy).
#pragma unroll
    for (int i = 0; i < 8; ++i) {
        __builtin_amdgcn_global_load_lds(
            (const __attribute__((address_space(1))) unsigned int*)(wsrc + (size_t)i * 4096 + (size_t)tid * 16),
            (__attribute__((address_space(3))) unsigned int*)(ldsb + i * 4096 + wave * 1024),
            16, 0, 0);
    }

    // ---- x load+convert through 4-deep ring (unit u: rt = u>>2, ks = u&3) ----
    const int rbase = wave * 32;
    const float* r0p = xn + (size_t)(rbase + l15) * 128 + lhi * 8;
    const float* r1p = r0p + (size_t)16 * 128;
    bf16x8 afrag[2][4];
    f32x4 ring[4][2];
#pragma unroll
    for (int u = 0; u < 4; ++u) {
        const f32x4* p = (const f32x4*)(r0p + (u & 3) * 32);
        ring[u][0] = p[0];
        ring[u][1] = p[1];
    }
#pragma unroll
    for (int u = 0; u < 8; ++u) {
        f32x4 a0 = ring[u & 3][0];
        f32x4 a1 = ring[u & 3][1];
        if (u < 4) {
            const f32x4* p = (const f32x4*)(r1p + (u & 3) * 32);
            ring[u & 3][0] = p[0];
            ring[u & 3][1] = p[1];
        }
        union { bf16x8 vv; unsigned int uu[4]; } f;
        f.uu[0] = pkbf(a0.x, a0.y);
        f.uu[1] = pkbf(a0.z, a0.w);
        f.uu[2] = pkbf(a1.x, a1.y);
        f.uu[3] = pkbf(a1.z, a1.w);
        afrag[u >> 2][u & 3] = f.vv;
        __builtin_amdgcn_sched_barrier(0);   // hold the 4-deep pipeline shape
    }

    __syncthreads();   // W staging visible (barrier drains vmcnt)

    // ---- GEMM1 (swapped): D[o][m] = mfma(Wfrag, Xfrag); 4 phases x 2 ct ----
    // h layout: byte = ct*4096 + m*32 + slot*16 + sub, slot = s ^ ((m>>2)&1)
    f32x4 ccA = *(const f32x4*)(cd + 0 * 16 + lhi * 4);
    f32x4 ccB = *(const f32x4*)(cd + 1 * 16 + lhi * 4);
#pragma unroll
    for (int p = 0; p < 4; ++p) {
        const int ct0 = 2 * p, ct1 = 2 * p + 1;
        bf16x8 bf0[4], bf1[4];
#pragma unroll
        for (int ks = 0; ks < 4; ++ks) {
            bf0[ks] = *(const bf16x8*)(ldsb + ct0 * 4096 + ks * 1024 + lane * 16);
            bf1[ks] = *(const bf16x8*)(ldsb + ct1 * 4096 + ks * 1024 + lane * 16);
        }
        f32x4 acc0[2] = {{0.f,0.f,0.f,0.f},{0.f,0.f,0.f,0.f}};
        f32x4 acc1[2] = {{0.f,0.f,0.f,0.f},{0.f,0.f,0.f,0.f}};
#pragma unroll
        for (int ks = 0; ks < 4; ++ks) {
#pragma unroll
            for (int rt = 0; rt < 2; ++rt) {
                acc0[rt] = __builtin_amdgcn_mfma_f32_16x16x32_bf16(bf0[ks], afrag[rt][ks], acc0[rt], 0, 0, 0);
                acc1[rt] = __builtin_amdgcn_mfma_f32_16x16x32_bf16(bf1[ks], afrag[rt][ks], acc1[rt], 0, 0, 0);
            }
        }
        // prefetch next phase's bias across the barrier
        const int ctn = (p < 3) ? (2 * p + 2) : 0;
        f32x4 ccA_n = *(const f32x4*)(cd + ctn * 16 + lhi * 4);
        f32x4 ccB_n = *(const f32x4*)(cd + (ctn + 1) * 16 + lhi * 4);

        __syncthreads();   // all waves done reading W regions ct0,ct1

#pragma unroll
        for (int rt = 0; rt < 2; ++rt) {
            const int m = rbase + rt * 16 + l15;
            const int slot = ((lhi >> 1) ^ ((m >> 2) & 1));
            {
                float h0v = fmaxf(acc0[rt][0] + ccA.x, 0.f);
                float h1v = fmaxf(acc0[rt][1] + ccA.y, 0.f);
                float h2v = fmaxf(acc0[rt][2] + ccA.z, 0.f);
                float h3v = fmaxf(acc0[rt][3] + ccA.w, 0.f);
                union { unsigned int u[2]; unsigned long long ull; } pk;
                pk.u[0] = pkbf(h0v, h1v);
                pk.u[1] = pkbf(h2v, h3v);
                *(unsigned long long*)(ldsb + ct0 * 4096 + m * 32 + slot * 16 + (lhi & 1) * 8) = pk.ull;
            }
            {
                float h0v = fmaxf(acc1[rt][0] + ccB.x, 0.f);
                float h1v = fmaxf(acc1[rt][1] + ccB.y, 0.f);
                float h2v = fmaxf(acc1[rt][2] + ccB.z, 0.f);
                float h3v = fmaxf(acc1[rt][3] + ccB.w, 0.f);
                union { unsigned int u[2]; unsigned long long ull; } pk;
                pk.u[0] = pkbf(h0v, h1v);
                pk.u[1] = pkbf(h2v, h3v);
                *(unsigned long long*)(ldsb + ct1 * 4096 + m * 32 + slot * 16 + (lhi & 1) * 8) = pk.ull;
            }
        }
        ccA = ccA_n;
        ccB = ccB_n;
    }
    __syncthreads();   // h fully visible

    // ---- GEMM2 (swapped): D[q][m] = mfma(h1frag, h0frag) ----
    const int mrow = wave * 16 + l15;     // h0 row (= out row)
    bf16x8 hb[4];
#pragma unroll
    for (int ks = 0; ks < 4; ++ks) {
        const int ct = ks * 2 + (lhi >> 1);
        const int s  = (lhi & 1) ^ ((mrow >> 2) & 1);
        hb[ks] = *(const bf16x8*)(ldsb + ct * 4096 + mrow * 32 + s * 16);
    }
    float* outn = out + (size_t)n * 4096;
#pragma unroll
    for (int qt = 0; qt < 4; ++qt) {
        const int qrow = 64 + qt * 16 + l15;    // h1 row (= out col base)
        f32x4 acc = {0.f, 0.f, 0.f, 0.f};
#pragma unroll
        for (int ks = 0; ks < 4; ++ks) {
            const int ct = ks * 2 + (lhi >> 1);
            const int s  = (lhi & 1) ^ ((qrow >> 2) & 1);
            bf16x8 ha = *(const bf16x8*)(ldsb + ct * 4096 + qrow * 32 + s * 16);
            acc = __builtin_amdgcn_mfma_f32_16x16x32_bf16(ha, hb[ks], acc, 0, 0, 0);
        }
        *(f32x4*)(outn + mrow * 64 + qt * 16 + lhi * 4) = acc;
    }
}

extern "C" void kernel_launch(void* const* d_in, const int* in_sizes, int n_in,
                              void* d_out, int out_size, void* d_ws, size_t ws_size,
                              hipStream_t stream) {
    const float* x   = (const float*)d_in[0];   // node_features [4096,2,64,128]
    const int*   deg = (const int*)d_in[1];     // [4096]
    const float* W_r = (const float*)d_in[2];   // [2,128,128]
    const float* b_r = (const float*)d_in[3];   // [2,128]
    const float* W0  = (const float*)d_in[4];   // [128,128]
    const float* b0  = (const float*)d_in[5];   // [128]
    float* out = (float*)d_out;                 // [4096,64,64]

    unsigned short* wfrag = (unsigned short*)d_ws;                    // 1 MB
    float* call = (float*)((unsigned short*)d_ws + 32 * 8 * 4 * 64 * 8); // +16 KB

    build_weights<<<256, 256, 0, stream>>>(W_r, b_r, W0, b0, wfrag, call);
    edge_kernel<<<4096, 256, 0, stream>>>(x, deg, wfrag, call, out);
}

// Round 9
// 74.993 us; speedup vs baseline: 1.1172x; 1.0021x over previous
//
#include <hip/hip_runtime.h>
#include <hip/hip_bf16.h>

// N=4096, PAIR=2, M=64, D=128, O=128, R=2, MAX_DEG=32
// h = relu(x @ (d*Wsum + W0) + (d*bsum + b0));  out[n] = h0 @ h1^T
//
// Round 8: VGPR-cliff attack. R5/R7 structure but:
//  - single-ct GEMM1 phases (bf 16 + acc 8 regs vs 32+16)
//  - bias vector staged to LDS via global_load_lds (no cc prefetch regs)
//  - __launch_bounds__(256,4) to enforce <=128 VGPR -> 4 blocks/CU.

typedef __attribute__((ext_vector_type(8))) short bf16x8;
typedef __attribute__((ext_vector_type(4))) float f32x4;

__device__ __forceinline__ unsigned int pkbf(float a, float b) {
    union { __hip_bfloat162 h; unsigned int u; } v;
    v.h = __float22bfloat162_rn(float2{a, b});
    return v.u;
}

__global__ __launch_bounds__(256) void build_weights(
    const float* __restrict__ W_r,  // [2,128,128]
    const float* __restrict__ b_r,  // [2,128]
    const float* __restrict__ W0,   // [128,128]
    const float* __restrict__ b0,   // [128]
    unsigned short* __restrict__ wfrag,  // [32][8*4*64*8]  (32 KB per deg)
    float* __restrict__ call)            // [32*128]
{
    int t = blockIdx.x * blockDim.x + threadIdx.x;   // 0..65535
    int lane = t & 63;
    int ks = (t >> 6) & 3;
    int ct = (t >> 8) & 7;
    int d  = (t >> 11) & 31;
    int o = ct * 16 + (lane & 15);
    int kbase = ks * 32 + (lane >> 4) * 8;
    unsigned int* dst = (unsigned int*)(wfrag + (size_t)t * 8);
#pragma unroll
    for (int j = 0; j < 4; ++j) {
        int k0 = kbase + 2 * j;
        float wA = (float)d * (W_r[k0 * 128 + o] + W_r[128 * 128 + k0 * 128 + o]) + W0[k0 * 128 + o];
        float wB = (float)d * (W_r[(k0 + 1) * 128 + o] + W_r[128 * 128 + (k0 + 1) * 128 + o]) + W0[(k0 + 1) * 128 + o];
        dst[j] = pkbf(wA, wB);
    }
    if (t < 32 * 128) {
        int dd = t >> 7, oo = t & 127;
        call[t] = (float)dd * (b_r[oo] + b_r[128 + oo]) + b0[oo];
    }
}

__global__ __launch_bounds__(256, 4) void edge_kernel(
    const float* __restrict__ x,    // [N,2,64,128] f32
    const int* __restrict__ deg,    // [N]
    const unsigned short* __restrict__ wfrag,
    const float* __restrict__ call,
    float* __restrict__ out)        // [N,64,64] f32
{
    __shared__ char ldsb[33280];   // [0,32K): W staging then h; [32K,+512): bias

    const int n = blockIdx.x;
    const int tid = threadIdx.x;
    const int wave = tid >> 6;
    const int lane = tid & 63;
    const int l15 = lane & 15;
    const int lhi = lane >> 4;      // 0..3
    const int d = deg[n];

    const float* xn = x + (size_t)n * (2 * 64 * 128);
    const char* wsrc = (const char*)(wfrag + (size_t)d * (8 * 4 * 64 * 8));
    const float* cd = call + d * 128;

    // ---- W staging: global -> LDS direct (no VGPR roundtrip) ----
#pragma unroll
    for (int i = 0; i < 8; ++i) {
        __builtin_amdgcn_global_load_lds(
            (const __attribute__((address_space(1))) unsigned int*)(wsrc + (size_t)i * 4096 + (size_t)tid * 16),
            (__attribute__((address_space(3))) unsigned int*)(ldsb + i * 4096 + wave * 1024),
            16, 0, 0);
    }
    // ---- bias staging: 512 B, lanes 0..31 of wave 0 ----
    if (tid < 32) {
        __builtin_amdgcn_global_load_lds(
            (const __attribute__((address_space(1))) unsigned int*)(cd + tid * 4),
            (__attribute__((address_space(3))) unsigned int*)(ldsb + 32768),
            16, 0, 0);
    }

    // ---- x load+convert through 4-deep ring (unit u: rt = u>>2, ks = u&3) ----
    const int rbase = wave * 32;
    const float* r0p = xn + (size_t)(rbase + l15) * 128 + lhi * 8;
    const float* r1p = r0p + (size_t)16 * 128;
    bf16x8 afrag[2][4];
    f32x4 ring[4][2];
#pragma unroll
    for (int u = 0; u < 4; ++u) {
        const f32x4* p = (const f32x4*)(r0p + (u & 3) * 32);
        ring[u][0] = p[0];
        ring[u][1] = p[1];
    }
#pragma unroll
    for (int u = 0; u < 8; ++u) {
        f32x4 a0 = ring[u & 3][0];
        f32x4 a1 = ring[u & 3][1];
        if (u < 4) {
            const f32x4* p = (const f32x4*)(r1p + (u & 3) * 32);
            ring[u & 3][0] = p[0];
            ring[u & 3][1] = p[1];
        }
        union { bf16x8 vv; unsigned int uu[4]; } f;
        f.uu[0] = pkbf(a0.x, a0.y);
        f.uu[1] = pkbf(a0.z, a0.w);
        f.uu[2] = pkbf(a1.x, a1.y);
        f.uu[3] = pkbf(a1.z, a1.w);
        afrag[u >> 2][u & 3] = f.vv;
        __builtin_amdgcn_sched_barrier(0);   // hold the 4-deep pipeline shape
    }

    __syncthreads();   // W + bias staging visible (barrier drains vmcnt)

    // ---- GEMM1 (swapped): D[o][m] = mfma(Wfrag, Xfrag); 8 single-ct phases ----
    // h layout: byte = ct*4096 + m*32 + slot*16 + sub, slot = (lhi>>1)^((m>>2)&1)
#pragma unroll
    for (int ct = 0; ct < 8; ++ct) {
        bf16x8 bfrag[4];
#pragma unroll
        for (int ks = 0; ks < 4; ++ks)
            bfrag[ks] = *(const bf16x8*)(ldsb + ct * 4096 + ks * 1024 + lane * 16);
        f32x4 acc[2] = {{0.f,0.f,0.f,0.f},{0.f,0.f,0.f,0.f}};
#pragma unroll
        for (int ks = 0; ks < 4; ++ks)
#pragma unroll
            for (int rt = 0; rt < 2; ++rt)
                acc[rt] = __builtin_amdgcn_mfma_f32_16x16x32_bf16(bfrag[ks], afrag[rt][ks], acc[rt], 0, 0, 0);
        const f32x4 cc4 = *(const f32x4*)(ldsb + 32768 + ct * 64 + lhi * 16);

        __syncthreads();   // all waves done reading W region ct

#pragma unroll
        for (int rt = 0; rt < 2; ++rt) {
            const int m = rbase + rt * 16 + l15;
            const int slot = ((lhi >> 1) ^ ((m >> 2) & 1));
            float h0v = fmaxf(acc[rt][0] + cc4.x, 0.f);
            float h1v = fmaxf(acc[rt][1] + cc4.y, 0.f);
            float h2v = fmaxf(acc[rt][2] + cc4.z, 0.f);
            float h3v = fmaxf(acc[rt][3] + cc4.w, 0.f);
            union { unsigned int u[2]; unsigned long long ull; } pk;
            pk.u[0] = pkbf(h0v, h1v);
            pk.u[1] = pkbf(h2v, h3v);
            *(unsigned long long*)(ldsb + ct * 4096 + m * 32 + slot * 16 + (lhi & 1) * 8) = pk.ull;
        }
    }
    __syncthreads();   // h fully visible

    // ---- GEMM2 (swapped): D[q][m] = mfma(h1frag, h0frag) ----
    const int mrow = wave * 16 + l15;     // h0 row (= out row)
    bf16x8 hb[4];
#pragma unroll
    for (int ks = 0; ks < 4; ++ks) {
        const int ct = ks * 2 + (lhi >> 1);
        const int s  = (lhi & 1) ^ ((mrow >> 2) & 1);
        hb[ks] = *(const bf16x8*)(ldsb + ct * 4096 + mrow * 32 + s * 16);
    }
    float* outn = out + (size_t)n * 4096;
#pragma unroll
    for (int qt = 0; qt < 4; ++qt) {
        const int qrow = 64 + qt * 16 + l15;    // h1 row (= out col base)
        f32x4 acc = {0.f, 0.f, 0.f, 0.f};
#pragma unroll
        for (int ks = 0; ks < 4; ++ks) {
            const int ct = ks * 2 + (lhi >> 1);
            const int s  = (lhi & 1) ^ ((qrow >> 2) & 1);
            bf16x8 ha = *(const bf16x8*)(ldsb + ct * 4096 + qrow * 32 + s * 16);
            acc = __builtin_amdgcn_mfma_f32_16x16x32_bf16(ha, hb[ks], acc, 0, 0, 0);
        }
        *(f32x4*)(outn + mrow * 64 + qt * 16 + lhi * 4) = acc;
    }
}

extern "C" void kernel_launch(void* const* d_in, const int* in_sizes, int n_in,
                              void* d_out, int out_size, void* d_ws, size_t ws_size,
                              hipStream_t stream) {
    const float* x   = (const float*)d_in[0];   // node_features [4096,2,64,128]
    const int*   deg = (const int*)d_in[1];     // [4096]
    const float* W_r = (const float*)d_in[2];   // [2,128,128]
    const float* b_r = (const float*)d_in[3];   // [2,128]
    const float* W0  = (const float*)d_in[4];   // [128,128]
    const float* b0  = (const float*)d_in[5];   // [128]
    float* out = (float*)d_out;                 // [4096,64,64]

    unsigned short* wfrag = (unsigned short*)d_ws;                    // 1 MB
    float* call = (float*)((unsigned short*)d_ws + 32 * 8 * 4 * 64 * 8); // +16 KB

    build_weights<<<256, 256, 0, stream>>>(W_r, b_r, W0, b0, wfrag, call);
    edge_kernel<<<4096, 256, 0, stream>>>(x, deg, wfrag, call, out);
}